// Round 1
// baseline (408.292 us; speedup 1.0000x reference)
//
#include <hip/hip_runtime.h>
#include <hip/hip_bf16.h>

#define D 128

// ---------------------------------------------------------------- count edges
__global__ __launch_bounds__(256) void count_edges(const int* __restrict__ col,
                                                   int* __restrict__ cnt, int E) {
    int t = blockIdx.x * blockDim.x + threadIdx.x;
    if (t < E) atomicAdd(&cnt[col[t]], 1);
}

// ------------------------------------------------- scan: offsets, cursor, dis
// Single block, 1024 threads, 16 values/thread/chunk (16384 per chunk).
__global__ __launch_bounds__(1024) void scan_kernel(const int* __restrict__ cnt,
                                                    int* __restrict__ off,
                                                    int* __restrict__ cursor,
                                                    float* __restrict__ dis,
                                                    int N, int Etot) {
    __shared__ int wsum[16];
    __shared__ int s_carry;
    const int t = threadIdx.x, lane = t & 63, w = t >> 6;
    if (t == 0) s_carry = 0;
    __syncthreads();
    const int VPT = 16, CH = 1024 * VPT;
    for (int base = 0; base < N; base += CH) {
        int i0 = base + t * VPT;
        int v[VPT];
        int lsum = 0;
#pragma unroll
        for (int j = 0; j < VPT; ++j) {
            int i = i0 + j;
            v[j] = (i < N) ? cnt[i] + 1 : 0;   // +1 = self loop
            lsum += v[j];
        }
        // wave inclusive scan of lsum
        int sc = lsum;
#pragma unroll
        for (int s2 = 1; s2 < 64; s2 <<= 1) {
            int y = __shfl_up(sc, s2);
            if (lane >= s2) sc += y;
        }
        if (lane == 63) wsum[w] = sc;
        __syncthreads();
        int carry = s_carry;
        int woff = 0;
        for (int j = 0; j < w; ++j) woff += wsum[j];
        int run = carry + woff + sc - lsum;   // exclusive prefix of first elem
#pragma unroll
        for (int j = 0; j < VPT; ++j) {
            int i = i0 + j;
            if (i < N) {
                off[i] = run;
                cursor[i] = run;
                dis[i] = rsqrtf((float)v[j]);
            }
            run += v[j];
        }
        __syncthreads();
        if (t == 1023) s_carry = carry + woff + sc;
        __syncthreads();
    }
    if (t == 0) off[N] = Etot;
}

// ----------------------------------------------------------------- CSR fill
__global__ __launch_bounds__(256) void fill_edges(const int* __restrict__ row,
                                                  const int* __restrict__ col,
                                                  const float* __restrict__ dis,
                                                  int* __restrict__ cursor,
                                                  int* __restrict__ eidx,
                                                  float* __restrict__ enrm,
                                                  int E, int N) {
    int t = blockIdx.x * blockDim.x + threadIdx.x;
    if (t < E) {
        int r = row[t], c = col[t];
        int p = atomicAdd(&cursor[c], 1);
        eidx[p] = r;
        enrm[p] = dis[r] * dis[c];
    } else if (t < E + N) {
        int i = t - E;
        int p = atomicAdd(&cursor[i], 1);
        eidx[p] = i;
        float dd = dis[i];
        enrm[p] = dd * dd;
    }
}

// ------------------------------------------------------------- dense GEMM 128
// H[N,128] = X[N,128] @ W[128,128].  Block: 256 thr, 32 rows.
// Thread: 8 rows x 2 cols register tile.  W fully staged in LDS (64KB).
__global__ __launch_bounds__(256) void gemm_x128(const float* __restrict__ X,
                                                 const float* __restrict__ W,
                                                 float* __restrict__ H, int N) {
    __shared__ float Wl[128 * 128];   // 64 KB
    __shared__ float Xl[32 * 128];    // 16 KB
    const int t = threadIdx.x;
    for (int i = t; i < 128 * 128; i += 256) Wl[i] = W[i];
    const int rbase = blockIdx.x * 32;
    for (int i = t; i < 32 * 128; i += 256) {
        int r = rbase + (i >> 7);
        Xl[i] = (r < N) ? X[r * D + (i & 127)] : 0.f;
    }
    __syncthreads();
    const int cp = (t & 63) * 2;     // column pair
    const int rg = (t >> 6) * 8;     // row group of 8
    float acc[8][2];
#pragma unroll
    for (int i = 0; i < 8; ++i) { acc[i][0] = 0.f; acc[i][1] = 0.f; }
    for (int k = 0; k < 128; k += 4) {
        float2 wv[4];
#pragma unroll
        for (int kk = 0; kk < 4; ++kk)
            wv[kk] = *(const float2*)&Wl[(k + kk) * 128 + cp];
#pragma unroll
        for (int i = 0; i < 8; ++i) {
            float4 xv = *(const float4*)&Xl[(rg + i) * 128 + k];
            acc[i][0] += xv.x * wv[0].x + xv.y * wv[1].x + xv.z * wv[2].x + xv.w * wv[3].x;
            acc[i][1] += xv.x * wv[0].y + xv.y * wv[1].y + xv.z * wv[2].y + xv.w * wv[3].y;
        }
    }
#pragma unroll
    for (int i = 0; i < 8; ++i) {
        int r = rbase + rg + i;
        if (r < N) {
            H[r * D + cp]     = acc[i][0];
            H[r * D + cp + 1] = acc[i][1];
        }
    }
}

// --------------------------------------------------------- SpMM + bias + ReLU
// One block (128 thr) per target node; thread d owns feature d.
__global__ __launch_bounds__(128) void spmm_kernel(const float* __restrict__ H,
                                                   const int* __restrict__ off,
                                                   const int* __restrict__ eidx,
                                                   const float* __restrict__ enrm,
                                                   const float* __restrict__ bias,
                                                   float* __restrict__ O, int N) {
    int c = blockIdx.x;
    int d = threadIdx.x;
    int s = off[c], e = off[c + 1];
    float acc = bias[d];
    int k = s;
    for (; k + 4 <= e; k += 4) {
        int r0 = eidx[k], r1 = eidx[k + 1], r2 = eidx[k + 2], r3 = eidx[k + 3];
        float w0 = enrm[k], w1 = enrm[k + 1], w2 = enrm[k + 2], w3 = enrm[k + 3];
        float h0 = H[r0 * D + d], h1 = H[r1 * D + d];
        float h2 = H[r2 * D + d], h3 = H[r3 * D + d];
        acc += h0 * w0; acc += h1 * w1; acc += h2 * w2; acc += h3 * w3;
    }
    for (; k < e; ++k) acc += H[eidx[k] * D + d] * enrm[k];
    O[c * D + d] = fmaxf(acc, 0.f);
}

// ----------------------------------------------------------------- head GEMV
// One wave per node: out[i,0:3] = H[i,:] @ Wh + bh
__global__ __launch_bounds__(256) void head_kernel(const float* __restrict__ H,
                                                   const float* __restrict__ Wh,
                                                   const float* __restrict__ bh,
                                                   float* __restrict__ out, int N) {
    int gt = blockIdx.x * blockDim.x + threadIdx.x;
    int wid = gt >> 6;
    int lane = gt & 63;
    if (wid >= N) return;
    const float* hrow = H + (size_t)wid * D;
    float x0 = hrow[lane], x1 = hrow[lane + 64];
    float a0 = x0 * Wh[lane * 3 + 0] + x1 * Wh[(lane + 64) * 3 + 0];
    float a1 = x0 * Wh[lane * 3 + 1] + x1 * Wh[(lane + 64) * 3 + 1];
    float a2 = x0 * Wh[lane * 3 + 2] + x1 * Wh[(lane + 64) * 3 + 2];
#pragma unroll
    for (int s = 32; s > 0; s >>= 1) {
        a0 += __shfl_down(a0, s);
        a1 += __shfl_down(a1, s);
        a2 += __shfl_down(a2, s);
    }
    if (lane == 0) {
        out[wid * 3 + 0] = a0 + bh[0];
        out[wid * 3 + 1] = a1 + bh[1];
        out[wid * 3 + 2] = a2 + bh[2];
    }
}

// ---------------------------------------------------------------------------
extern "C" void kernel_launch(void* const* d_in, const int* in_sizes, int n_in,
                              void* d_out, int out_size, void* d_ws, size_t ws_size,
                              hipStream_t stream) {
    const float* x  = (const float*)d_in[0];
    const int*   ei = (const int*)d_in[1];
    const float* W1 = (const float*)d_in[2];
    const float* b1 = (const float*)d_in[3];
    const float* W2 = (const float*)d_in[4];
    const float* b2 = (const float*)d_in[5];
    const float* Wh = (const float*)d_in[6];
    const float* bh = (const float*)d_in[7];
    float* out = (float*)d_out;

    const int N = in_sizes[0] / D;       // 50000
    const int E = in_sizes[1] / 2;       // 800000
    const int Etot = E + N;              // edges incl. self loops
    const int* row = ei;
    const int* col = ei + E;

    // -------- workspace layout
    char* ws = (char*)d_ws;
    size_t o = 0;
    auto alloc = [&](size_t bytes) -> char* {
        char* p = ws + o;
        o = (o + bytes + 255) & ~(size_t)255;
        return p;
    };
    int*   cnt    = (int*)  alloc((size_t)N * 4);
    int*   off    = (int*)  alloc((size_t)(N + 1) * 4);
    int*   cursor = (int*)  alloc((size_t)N * 4);
    float* dis    = (float*)alloc((size_t)N * 4);
    int*   eidx   = (int*)  alloc((size_t)Etot * 4);
    float* enrm   = (float*)alloc((size_t)Etot * 4);
    float* A      = (float*)alloc((size_t)N * D * 4);
    float* B      = (float*)alloc((size_t)N * D * 4);
    (void)ws_size;

    hipMemsetAsync(cnt, 0, (size_t)N * 4, stream);
    count_edges<<<(E + 255) / 256, 256, 0, stream>>>(col, cnt, E);
    scan_kernel<<<1, 1024, 0, stream>>>(cnt, off, cursor, dis, N, Etot);
    fill_edges<<<(Etot + 255) / 256, 256, 0, stream>>>(row, col, dis, cursor,
                                                       eidx, enrm, E, N);

    int gblocks = (N + 31) / 32;
    gemm_x128<<<gblocks, 256, 0, stream>>>(x, W1, A, N);
    spmm_kernel<<<N, 128, 0, stream>>>(A, off, eidx, enrm, b1, B, N);
    gemm_x128<<<gblocks, 256, 0, stream>>>(B, W2, A, N);
    spmm_kernel<<<N, 128, 0, stream>>>(A, off, eidx, enrm, b2, B, N);
    head_kernel<<<((size_t)N * 64 + 255) / 256, 256, 0, stream>>>(B, Wh, bh, out, N);
}

// Round 2
// 325.499 us; speedup vs baseline: 1.2544x; 1.2544x over previous
//
#include <hip/hip_runtime.h>
#include <hip/hip_bf16.h>

#define D 128

// ---------------------------------------------------------------- count edges
__global__ __launch_bounds__(256) void count_edges(const int* __restrict__ col,
                                                   int* __restrict__ cnt, int E) {
    int t = blockIdx.x * blockDim.x + threadIdx.x;
    if (t < E) atomicAdd(&cnt[col[t]], 1);
}

// ------------------------------------------- scan phase A: block partial sums
// Also computes dis[i] = rsqrt(deg[i]) (deg = cnt+1, self loop included).
__global__ __launch_bounds__(256) void scan_partial(const int* __restrict__ cnt,
                                                    float* __restrict__ dis,
                                                    int* __restrict__ bsum, int N) {
    int i = blockIdx.x * 256 + threadIdx.x;
    int v = 0;
    if (i < N) {
        v = cnt[i] + 1;
        dis[i] = rsqrtf((float)v);
    }
    int s = v;
#pragma unroll
    for (int d = 1; d < 64; d <<= 1) s += __shfl_xor(s, d);
    __shared__ int ws[4];
    int lane = threadIdx.x & 63, w = threadIdx.x >> 6;
    if (lane == 0) ws[w] = s;
    __syncthreads();
    if (threadIdx.x == 0) bsum[blockIdx.x] = ws[0] + ws[1] + ws[2] + ws[3];
}

// --------------------------------- scan phase B: exclusive scan of block sums
// nb <= 256; single block of 256 threads.
__global__ __launch_bounds__(256) void scan_blocksums(const int* __restrict__ bsum,
                                                      int* __restrict__ boff, int nb) {
    int t = threadIdx.x;
    int v = (t < nb) ? bsum[t] : 0;
    int lane = t & 63, w = t >> 6;
    int sc = v;
#pragma unroll
    for (int d = 1; d < 64; d <<= 1) {
        int y = __shfl_up(sc, d);
        if (lane >= d) sc += y;
    }
    __shared__ int ws[4];
    if (lane == 63) ws[w] = sc;
    __syncthreads();
    int add = 0;
    for (int j = 0; j < w; ++j) add += ws[j];
    if (t < nb) boff[t] = add + sc - v;   // exclusive prefix
}

// ------------------------------- scan phase C: final offsets (off and cursor)
__global__ __launch_bounds__(256) void scan_final(const int* __restrict__ cnt,
                                                  const int* __restrict__ boff,
                                                  int* __restrict__ off,
                                                  int* __restrict__ cursor,
                                                  int N, int Etot) {
    int i = blockIdx.x * 256 + threadIdx.x;
    int v = (i < N) ? cnt[i] + 1 : 0;
    int lane = threadIdx.x & 63, w = threadIdx.x >> 6;
    int sc = v;
#pragma unroll
    for (int d = 1; d < 64; d <<= 1) {
        int y = __shfl_up(sc, d);
        if (lane >= d) sc += y;
    }
    __shared__ int ws[4];
    if (lane == 63) ws[w] = sc;
    __syncthreads();
    int add = boff[blockIdx.x];
    for (int j = 0; j < w; ++j) add += ws[j];
    int ex = add + sc - v;
    if (i < N) {
        off[i] = ex;
        cursor[i] = ex;
    }
    if (i == 0 && blockIdx.x == 0) off[N] = Etot;
}

// ----------------------------------------------------------------- CSR fill
__global__ __launch_bounds__(256) void fill_edges(const int* __restrict__ row,
                                                  const int* __restrict__ col,
                                                  const float* __restrict__ dis,
                                                  int* __restrict__ cursor,
                                                  int* __restrict__ eidx,
                                                  float* __restrict__ enrm,
                                                  int E, int N) {
    int t = blockIdx.x * blockDim.x + threadIdx.x;
    if (t < E) {
        int r = row[t], c = col[t];
        int p = atomicAdd(&cursor[c], 1);
        eidx[p] = r;
        enrm[p] = dis[r] * dis[c];
    } else if (t < E + N) {
        int i = t - E;
        int p = atomicAdd(&cursor[i], 1);
        eidx[p] = i;
        float dd = dis[i];
        enrm[p] = dd * dd;
    }
}

// ------------------------------------------------------------- dense GEMM 128
// H[N,128] = X[N,128] @ W[128,128].  Block: 256 thr, 32 rows.
// Thread: 8 rows x 2 cols register tile.  W fully staged in LDS (64KB).
__global__ __launch_bounds__(256) void gemm_x128(const float* __restrict__ X,
                                                 const float* __restrict__ W,
                                                 float* __restrict__ H, int N) {
    __shared__ float Wl[128 * 128];   // 64 KB
    __shared__ float Xl[32 * 128];    // 16 KB
    const int t = threadIdx.x;
    for (int i = t; i < 128 * 128; i += 256) Wl[i] = W[i];
    const int rbase = blockIdx.x * 32;
    for (int i = t; i < 32 * 128; i += 256) {
        int r = rbase + (i >> 7);
        Xl[i] = (r < N) ? X[r * D + (i & 127)] : 0.f;
    }
    __syncthreads();
    const int cp = (t & 63) * 2;     // column pair
    const int rg = (t >> 6) * 8;     // row group of 8
    float acc[8][2];
#pragma unroll
    for (int i = 0; i < 8; ++i) { acc[i][0] = 0.f; acc[i][1] = 0.f; }
    for (int k = 0; k < 128; k += 4) {
        float2 wv[4];
#pragma unroll
        for (int kk = 0; kk < 4; ++kk)
            wv[kk] = *(const float2*)&Wl[(k + kk) * 128 + cp];
#pragma unroll
        for (int i = 0; i < 8; ++i) {
            float4 xv = *(const float4*)&Xl[(rg + i) * 128 + k];
            acc[i][0] += xv.x * wv[0].x + xv.y * wv[1].x + xv.z * wv[2].x + xv.w * wv[3].x;
            acc[i][1] += xv.x * wv[0].y + xv.y * wv[1].y + xv.z * wv[2].y + xv.w * wv[3].y;
        }
    }
#pragma unroll
    for (int i = 0; i < 8; ++i) {
        int r = rbase + rg + i;
        if (r < N) {
            H[r * D + cp]     = acc[i][0];
            H[r * D + cp + 1] = acc[i][1];
        }
    }
}

// --------------------------------------------------------- SpMM + bias + ReLU
// One block (128 thr) per target node; thread d owns feature d.
__global__ __launch_bounds__(128) void spmm_kernel(const float* __restrict__ H,
                                                   const int* __restrict__ off,
                                                   const int* __restrict__ eidx,
                                                   const float* __restrict__ enrm,
                                                   const float* __restrict__ bias,
                                                   float* __restrict__ O, int N) {
    int c = blockIdx.x;
    int d = threadIdx.x;
    int s = off[c], e = off[c + 1];
    float acc = bias[d];
    int k = s;
    for (; k + 4 <= e; k += 4) {
        int r0 = eidx[k], r1 = eidx[k + 1], r2 = eidx[k + 2], r3 = eidx[k + 3];
        float w0 = enrm[k], w1 = enrm[k + 1], w2 = enrm[k + 2], w3 = enrm[k + 3];
        float h0 = H[r0 * D + d], h1 = H[r1 * D + d];
        float h2 = H[r2 * D + d], h3 = H[r3 * D + d];
        acc += h0 * w0; acc += h1 * w1; acc += h2 * w2; acc += h3 * w3;
    }
    for (; k < e; ++k) acc += H[eidx[k] * D + d] * enrm[k];
    O[c * D + d] = fmaxf(acc, 0.f);
}

// ----------------------------------------------------------------- head GEMV
// One wave per node: out[i,0:3] = H[i,:] @ Wh + bh
__global__ __launch_bounds__(256) void head_kernel(const float* __restrict__ H,
                                                   const float* __restrict__ Wh,
                                                   const float* __restrict__ bh,
                                                   float* __restrict__ out, int N) {
    int gt = blockIdx.x * blockDim.x + threadIdx.x;
    int wid = gt >> 6;
    int lane = gt & 63;
    if (wid >= N) return;
    const float* hrow = H + (size_t)wid * D;
    float x0 = hrow[lane], x1 = hrow[lane + 64];
    float a0 = x0 * Wh[lane * 3 + 0] + x1 * Wh[(lane + 64) * 3 + 0];
    float a1 = x0 * Wh[lane * 3 + 1] + x1 * Wh[(lane + 64) * 3 + 1];
    float a2 = x0 * Wh[lane * 3 + 2] + x1 * Wh[(lane + 64) * 3 + 2];
#pragma unroll
    for (int s = 32; s > 0; s >>= 1) {
        a0 += __shfl_down(a0, s);
        a1 += __shfl_down(a1, s);
        a2 += __shfl_down(a2, s);
    }
    if (lane == 0) {
        out[wid * 3 + 0] = a0 + bh[0];
        out[wid * 3 + 1] = a1 + bh[1];
        out[wid * 3 + 2] = a2 + bh[2];
    }
}

// ---------------------------------------------------------------------------
extern "C" void kernel_launch(void* const* d_in, const int* in_sizes, int n_in,
                              void* d_out, int out_size, void* d_ws, size_t ws_size,
                              hipStream_t stream) {
    const float* x  = (const float*)d_in[0];
    const int*   ei = (const int*)d_in[1];
    const float* W1 = (const float*)d_in[2];
    const float* b1 = (const float*)d_in[3];
    const float* W2 = (const float*)d_in[4];
    const float* b2 = (const float*)d_in[5];
    const float* Wh = (const float*)d_in[6];
    const float* bh = (const float*)d_in[7];
    float* out = (float*)d_out;

    const int N = in_sizes[0] / D;       // 50000
    const int E = in_sizes[1] / 2;       // 800000
    const int Etot = E + N;              // edges incl. self loops
    const int* row = ei;
    const int* col = ei + E;

    // -------- workspace layout
    char* ws = (char*)d_ws;
    size_t o = 0;
    auto alloc = [&](size_t bytes) -> char* {
        char* p = ws + o;
        o = (o + bytes + 255) & ~(size_t)255;
        return p;
    };
    const int nb = (N + 255) / 256;      // scan blocks (196)
    int*   cnt    = (int*)  alloc((size_t)N * 4);
    int*   off    = (int*)  alloc((size_t)(N + 1) * 4);
    int*   cursor = (int*)  alloc((size_t)N * 4);
    float* dis    = (float*)alloc((size_t)N * 4);
    int*   bsum   = (int*)  alloc((size_t)nb * 4);
    int*   boff   = (int*)  alloc((size_t)nb * 4);
    int*   eidx   = (int*)  alloc((size_t)Etot * 4);
    float* enrm   = (float*)alloc((size_t)Etot * 4);
    float* A      = (float*)alloc((size_t)N * D * 4);
    float* B      = (float*)alloc((size_t)N * D * 4);
    (void)ws_size;

    hipMemsetAsync(cnt, 0, (size_t)N * 4, stream);
    count_edges<<<(E + 255) / 256, 256, 0, stream>>>(col, cnt, E);
    scan_partial<<<nb, 256, 0, stream>>>(cnt, dis, bsum, N);
    scan_blocksums<<<1, 256, 0, stream>>>(bsum, boff, nb);
    scan_final<<<nb, 256, 0, stream>>>(cnt, boff, off, cursor, N, Etot);
    fill_edges<<<(Etot + 255) / 256, 256, 0, stream>>>(row, col, dis, cursor,
                                                       eidx, enrm, E, N);

    int gblocks = (N + 31) / 32;
    gemm_x128<<<gblocks, 256, 0, stream>>>(x, W1, A, N);
    spmm_kernel<<<N, 128, 0, stream>>>(A, off, eidx, enrm, b1, B, N);
    gemm_x128<<<gblocks, 256, 0, stream>>>(B, W2, A, N);
    spmm_kernel<<<N, 128, 0, stream>>>(A, off, eidx, enrm, b2, B, N);
    head_kernel<<<((size_t)N * 64 + 255) / 256, 256, 0, stream>>>(B, Wh, bh, out, N);
}

// Round 3
// 291.185 us; speedup vs baseline: 1.4022x; 1.1178x over previous
//
#include <hip/hip_runtime.h>
#include <hip/hip_bf16.h>

#define D 128
#define XSTRIDE 68   // 256B+16B row pitch: wave's 4 row-groups land in distinct bank quads

// ---------------------------------------------------------------- count edges
__global__ __launch_bounds__(256) void count_edges(const int* __restrict__ col,
                                                   int* __restrict__ cnt, int E) {
    int t = blockIdx.x * blockDim.x + threadIdx.x;
    if (t < E) atomicAdd(&cnt[col[t]], 1);
}

// ------------------------------------------- scan phase A: block partial sums
__global__ __launch_bounds__(256) void scan_partial(const int* __restrict__ cnt,
                                                    float* __restrict__ dis,
                                                    int* __restrict__ bsum, int N) {
    int i = blockIdx.x * 256 + threadIdx.x;
    int v = 0;
    if (i < N) {
        v = cnt[i] + 1;
        dis[i] = rsqrtf((float)v);
    }
    int s = v;
#pragma unroll
    for (int d = 1; d < 64; d <<= 1) s += __shfl_xor(s, d);
    __shared__ int ws[4];
    int lane = threadIdx.x & 63, w = threadIdx.x >> 6;
    if (lane == 0) ws[w] = s;
    __syncthreads();
    if (threadIdx.x == 0) bsum[blockIdx.x] = ws[0] + ws[1] + ws[2] + ws[3];
}

// --------------------------------- scan phase B: exclusive scan of block sums
__global__ __launch_bounds__(256) void scan_blocksums(const int* __restrict__ bsum,
                                                      int* __restrict__ boff, int nb) {
    int t = threadIdx.x;
    int v = (t < nb) ? bsum[t] : 0;
    int lane = t & 63, w = t >> 6;
    int sc = v;
#pragma unroll
    for (int d = 1; d < 64; d <<= 1) {
        int y = __shfl_up(sc, d);
        if (lane >= d) sc += y;
    }
    __shared__ int ws[4];
    if (lane == 63) ws[w] = sc;
    __syncthreads();
    int add = 0;
    for (int j = 0; j < w; ++j) add += ws[j];
    if (t < nb) boff[t] = add + sc - v;
}

// ------------------------------- scan phase C: final offsets (off and cursor)
__global__ __launch_bounds__(256) void scan_final(const int* __restrict__ cnt,
                                                  const int* __restrict__ boff,
                                                  int* __restrict__ off,
                                                  int* __restrict__ cursor,
                                                  int N, int Etot) {
    int i = blockIdx.x * 256 + threadIdx.x;
    int v = (i < N) ? cnt[i] + 1 : 0;
    int lane = threadIdx.x & 63, w = threadIdx.x >> 6;
    int sc = v;
#pragma unroll
    for (int d = 1; d < 64; d <<= 1) {
        int y = __shfl_up(sc, d);
        if (lane >= d) sc += y;
    }
    __shared__ int ws[4];
    if (lane == 63) ws[w] = sc;
    __syncthreads();
    int add = boff[blockIdx.x];
    for (int j = 0; j < w; ++j) add += ws[j];
    int ex = add + sc - v;
    if (i < N) {
        off[i] = ex;
        cursor[i] = ex;
    }
    if (i == 0 && blockIdx.x == 0) off[N] = Etot;
}

// ----------------------------------------------------------------- CSR fill
__global__ __launch_bounds__(256) void fill_edges(const int* __restrict__ row,
                                                  const int* __restrict__ col,
                                                  const float* __restrict__ dis,
                                                  int* __restrict__ cursor,
                                                  int* __restrict__ eidx,
                                                  float* __restrict__ enrm,
                                                  int E, int N) {
    int t = blockIdx.x * blockDim.x + threadIdx.x;
    if (t < E) {
        int r = row[t], c = col[t];
        int p = atomicAdd(&cursor[c], 1);
        eidx[p] = r;
        enrm[p] = dis[r] * dis[c];
    } else if (t < E + N) {
        int i = t - E;
        int p = atomicAdd(&cursor[i], 1);
        eidx[p] = i;
        float dd = dis[i];
        enrm[p] = dd * dd;
    }
}

// ------------------------------------------------------------- dense GEMM 128
// H[N,128] = X[N,128] @ W[128,128].
// 512 thr (8 waves), 256 rows/block, per-thread 8 rows x 8 cols.
// cg = t&15 owns cols {4cg..4cg+3} u {64+4cg..67+4cg}  (wave reads a
// contiguous 64-word span of each W row -> 2-way bank alias = free).
// rg = t>>4 owns rows {rg + 32i}      (stride-68 X pitch -> distinct quads).
// X staged in two K-halves so W(64K)+X(68K)=132K fits LDS; 1 block/CU.
__global__ __launch_bounds__(512, 2) void gemm_tile(const float* __restrict__ X,
                                                    const float* __restrict__ W,
                                                    float* __restrict__ H, int N) {
    __shared__ float Wl[128 * 128];        // 64 KB, row-major [k][c]
    __shared__ float Xl[256 * XSTRIDE];    // 68 KB, [row][k-within-half]
    const int t = threadIdx.x;
    const int rbase = blockIdx.x * 256;

    // stage W (once): 4096 float4, 8 per thread, linear -> conflict-free
    for (int i = t; i < 4096; i += 512)
        *(float4*)&Wl[i * 4] = ((const float4*)W)[i];

    const int cg = t & 15;
    const int rg = t >> 4;
    float acc[8][8];
#pragma unroll
    for (int i = 0; i < 8; ++i)
#pragma unroll
        for (int j = 0; j < 8; ++j) acc[i][j] = 0.f;

    for (int half = 0; half < 2; ++half) {
        __syncthreads();   // W ready (iter 0); Xl reads of prev half done (iter 1)
        // stage X half: 256 rows x 64 k = 4096 float4
        for (int i = t; i < 4096; i += 512) {
            int r = i >> 4;               // 16 float4 per row
            int k2 = (i & 15) << 2;
            int gr = rbase + r;
            float4 v;
            if (gr < N) v = *(const float4*)&X[(size_t)gr * D + half * 64 + k2];
            else { v.x = v.y = v.z = v.w = 0.f; }
            *(float4*)&Xl[r * XSTRIDE + k2] = v;
        }
        __syncthreads();

        for (int k = 0; k < 64; k += 4) {
            const int kb = half * 64 + k;
            float4 wv0[4], wv1[4];
#pragma unroll
            for (int kk = 0; kk < 4; ++kk) {
                wv0[kk] = *(const float4*)&Wl[(kb + kk) * D + cg * 4];
                wv1[kk] = *(const float4*)&Wl[(kb + kk) * D + 64 + cg * 4];
            }
#pragma unroll
            for (int i = 0; i < 8; ++i) {
                float4 xv = *(const float4*)&Xl[(rg + 32 * i) * XSTRIDE + k];
                acc[i][0] += xv.x * wv0[0].x + xv.y * wv0[1].x + xv.z * wv0[2].x + xv.w * wv0[3].x;
                acc[i][1] += xv.x * wv0[0].y + xv.y * wv0[1].y + xv.z * wv0[2].y + xv.w * wv0[3].y;
                acc[i][2] += xv.x * wv0[0].z + xv.y * wv0[1].z + xv.z * wv0[2].z + xv.w * wv0[3].z;
                acc[i][3] += xv.x * wv0[0].w + xv.y * wv0[1].w + xv.z * wv0[2].w + xv.w * wv0[3].w;
                acc[i][4] += xv.x * wv1[0].x + xv.y * wv1[1].x + xv.z * wv1[2].x + xv.w * wv1[3].x;
                acc[i][5] += xv.x * wv1[0].y + xv.y * wv1[1].y + xv.z * wv1[2].y + xv.w * wv1[3].y;
                acc[i][6] += xv.x * wv1[0].z + xv.y * wv1[1].z + xv.z * wv1[2].z + xv.w * wv1[3].z;
                acc[i][7] += xv.x * wv1[0].w + xv.y * wv1[1].w + xv.z * wv1[2].w + xv.w * wv1[3].w;
            }
        }
    }

#pragma unroll
    for (int i = 0; i < 8; ++i) {
        int r = rbase + rg + 32 * i;
        if (r < N) {
            float4 o0, o1;
            o0.x = acc[i][0]; o0.y = acc[i][1]; o0.z = acc[i][2]; o0.w = acc[i][3];
            o1.x = acc[i][4]; o1.y = acc[i][5]; o1.z = acc[i][6]; o1.w = acc[i][7];
            *(float4*)&H[(size_t)r * D + cg * 4]      = o0;
            *(float4*)&H[(size_t)r * D + 64 + cg * 4] = o1;
        }
    }
}

// --------------------------------------------------------- SpMM + bias + ReLU
// One block (128 thr) per target node; thread d owns feature d.
__global__ __launch_bounds__(128) void spmm_kernel(const float* __restrict__ H,
                                                   const int* __restrict__ off,
                                                   const int* __restrict__ eidx,
                                                   const float* __restrict__ enrm,
                                                   const float* __restrict__ bias,
                                                   float* __restrict__ O, int N) {
    int c = blockIdx.x;
    int d = threadIdx.x;
    int s = off[c], e = off[c + 1];
    float acc = bias[d];
    int k = s;
    for (; k + 4 <= e; k += 4) {
        int r0 = eidx[k], r1 = eidx[k + 1], r2 = eidx[k + 2], r3 = eidx[k + 3];
        float w0 = enrm[k], w1 = enrm[k + 1], w2 = enrm[k + 2], w3 = enrm[k + 3];
        float h0 = H[r0 * D + d], h1 = H[r1 * D + d];
        float h2 = H[r2 * D + d], h3 = H[r3 * D + d];
        acc += h0 * w0; acc += h1 * w1; acc += h2 * w2; acc += h3 * w3;
    }
    for (; k < e; ++k) acc += H[eidx[k] * D + d] * enrm[k];
    O[c * D + d] = fmaxf(acc, 0.f);
}

// ----------------------------------------------------------------- head GEMV
__global__ __launch_bounds__(256) void head_kernel(const float* __restrict__ H,
                                                   const float* __restrict__ Wh,
                                                   const float* __restrict__ bh,
                                                   float* __restrict__ out, int N) {
    int gt = blockIdx.x * blockDim.x + threadIdx.x;
    int wid = gt >> 6;
    int lane = gt & 63;
    if (wid >= N) return;
    const float* hrow = H + (size_t)wid * D;
    float x0 = hrow[lane], x1 = hrow[lane + 64];
    float a0 = x0 * Wh[lane * 3 + 0] + x1 * Wh[(lane + 64) * 3 + 0];
    float a1 = x0 * Wh[lane * 3 + 1] + x1 * Wh[(lane + 64) * 3 + 1];
    float a2 = x0 * Wh[lane * 3 + 2] + x1 * Wh[(lane + 64) * 3 + 2];
#pragma unroll
    for (int s = 32; s > 0; s >>= 1) {
        a0 += __shfl_down(a0, s);
        a1 += __shfl_down(a1, s);
        a2 += __shfl_down(a2, s);
    }
    if (lane == 0) {
        out[wid * 3 + 0] = a0 + bh[0];
        out[wid * 3 + 1] = a1 + bh[1];
        out[wid * 3 + 2] = a2 + bh[2];
    }
}

// ---------------------------------------------------------------------------
extern "C" void kernel_launch(void* const* d_in, const int* in_sizes, int n_in,
                              void* d_out, int out_size, void* d_ws, size_t ws_size,
                              hipStream_t stream) {
    const float* x  = (const float*)d_in[0];
    const int*   ei = (const int*)d_in[1];
    const float* W1 = (const float*)d_in[2];
    const float* b1 = (const float*)d_in[3];
    const float* W2 = (const float*)d_in[4];
    const float* b2 = (const float*)d_in[5];
    const float* Wh = (const float*)d_in[6];
    const float* bh = (const float*)d_in[7];
    float* out = (float*)d_out;

    const int N = in_sizes[0] / D;       // 50000
    const int E = in_sizes[1] / 2;       // 800000
    const int Etot = E + N;
    const int* row = ei;
    const int* col = ei + E;

    // -------- workspace layout
    char* ws = (char*)d_ws;
    size_t o = 0;
    auto alloc = [&](size_t bytes) -> char* {
        char* p = ws + o;
        o = (o + bytes + 255) & ~(size_t)255;
        return p;
    };
    const int nb = (N + 255) / 256;      // scan blocks (196)
    int*   cnt    = (int*)  alloc((size_t)N * 4);
    int*   off    = (int*)  alloc((size_t)(N + 1) * 4);
    int*   cursor = (int*)  alloc((size_t)N * 4);
    float* dis    = (float*)alloc((size_t)N * 4);
    int*   bsum   = (int*)  alloc((size_t)nb * 4);
    int*   boff   = (int*)  alloc((size_t)nb * 4);
    int*   eidx   = (int*)  alloc((size_t)Etot * 4);
    float* enrm   = (float*)alloc((size_t)Etot * 4);
    float* A      = (float*)alloc((size_t)N * D * 4);
    float* B      = (float*)alloc((size_t)N * D * 4);
    (void)ws_size;

    hipMemsetAsync(cnt, 0, (size_t)N * 4, stream);
    count_edges<<<(E + 255) / 256, 256, 0, stream>>>(col, cnt, E);
    scan_partial<<<nb, 256, 0, stream>>>(cnt, dis, bsum, N);
    scan_blocksums<<<1, 256, 0, stream>>>(bsum, boff, nb);
    scan_final<<<nb, 256, 0, stream>>>(cnt, boff, off, cursor, N, Etot);
    fill_edges<<<(Etot + 255) / 256, 256, 0, stream>>>(row, col, dis, cursor,
                                                       eidx, enrm, E, N);

    int gblocks = (N + 255) / 256;       // 256 rows per block
    gemm_tile<<<gblocks, 512, 0, stream>>>(x, W1, A, N);
    spmm_kernel<<<N, 128, 0, stream>>>(A, off, eidx, enrm, b1, B, N);
    gemm_tile<<<gblocks, 512, 0, stream>>>(B, W2, A, N);
    spmm_kernel<<<N, 128, 0, stream>>>(A, off, eidx, enrm, b2, B, N);
    head_kernel<<<((size_t)N * 64 + 255) / 256, 256, 0, stream>>>(B, Wh, bh, out, N);
}